// Round 7
// baseline (2157.608 us; speedup 1.0000x reference)
//
#include <hip/hip_runtime.h>

typedef _Float16 half2v __attribute__((ext_vector_type(2)));
typedef __fp16 pk2 __attribute__((ext_vector_type(2)));

#define T_LEN 1024
#define NBATCH 1024
#define HID 20
#define G_B 2   // batch elements per wave (lane groups of 20)

#if defined(__has_builtin)
#if __has_builtin(__builtin_amdgcn_fdot2)
#define HAVE_FDOT2 1
#endif
#if __has_builtin(__builtin_amdgcn_cvt_pkrtz)
#define HAVE_PKRTZ 1
#endif
#endif

__device__ __forceinline__ float fdot2_(half2v a, half2v b, float c) {
#ifdef HAVE_FDOT2
    return __builtin_amdgcn_fdot2(a, b, c, false);
#else
    return c + (float)a[0] * (float)b[0] + (float)a[1] * (float)b[1];
#endif
}

__device__ __forceinline__ half2v pack_rtz(float a, float b) {
#ifdef HAVE_PKRTZ
    pk2 p = __builtin_amdgcn_cvt_pkrtz(a, b);
    return __builtin_bit_cast(half2v, p);
#else
    half2v r; r[0] = (_Float16)a; r[1] = (_Float16)b; return r;
#endif
}

__device__ __forceinline__ half2v pack2(float a, float b) {
    half2v r; r[0] = (_Float16)a; r[1] = (_Float16)b; return r;
}

__device__ __forceinline__ float sigm(float z) {
    return 1.0f / (1.0f + __expf(-z));
}
__device__ __forceinline__ float tanh_s(float z) {
    return 2.0f / (1.0f + __expf(-2.0f * z)) - 1.0f;
}

// Distribute scalar h (held per-lane: lane gb+j owns h[j]) to all lanes of
// the group as 10 packed half2: 20 parallel shfls + 10 pack-cvt.
__device__ __forceinline__ void distribute(float hn, int gb, half2v hd[10]) {
#pragma unroll
    for (int k = 0; k < 10; ++k) {
        float e = __shfl(hn, gb + 2 * k, 64);
        float o = __shfl(hn, gb + 2 * k + 1, 64);
        hd[k] = pack_rtz(e, o);
    }
}

// One wave per G_B=2 batch elements; ALL 3 layers in-wave, in-register.
// Lane layout: lanes 0..19 batch b0 unit j=lane; lanes 20..39 batch b1 unit
// j=lane-20; lanes 40..63 idle (mirror lane 0, never write).
// Each lane owns all 4 gates (rows j, 20+j, 40+j, 60+j) of its unit:
// c/h update is lane-local; h distribution via 20 shfls (no LDS, no barrier).
__global__ void __launch_bounds__(64, 1) lstm3_wave(
    const float* __restrict__ x,
    const float* __restrict__ wih0, const float* __restrict__ whh0,
    const float* __restrict__ bih0, const float* __restrict__ bhh0,
    const float* __restrict__ wih1, const float* __restrict__ whh1,
    const float* __restrict__ bih1, const float* __restrict__ bhh1,
    const float* __restrict__ wih2, const float* __restrict__ whh2,
    const float* __restrict__ bih2, const float* __restrict__ bhh2,
    const float* __restrict__ fcw, const float* __restrict__ fcb,
    float* __restrict__ out)
{
    __shared__ __align__(16) float xlds[G_B * T_LEN];  // 8 KB staged input
    __shared__ float hfin[G_B][HID];

    const int tid = threadIdx.x;
    const long b_base = (long)blockIdx.x * G_B;

    // stage x: G_B contiguous rows, coalesced float4
    {
        const float4* x4 = (const float4*)(x + b_base * T_LEN);
        float4* xl4 = (float4*)xlds;
#pragma unroll
        for (int i = 0; i < G_B * T_LEN / 4 / 64; ++i)
            xl4[tid + 64 * i] = x4[tid + 64 * i];
    }

    const bool act = tid < G_B * HID;
    const int g = act ? (tid / HID) : 0;
    const int j = act ? (tid % HID) : 0;
    const int gb = g * HID;

    const float* whh_l[3] = {whh0, whh1, whh2};
    const float* wih_l[3] = {wih0, wih1, wih2};
    const float* bih_l[3] = {bih0, bih1, bih2};
    const float* bhh_l[3] = {bhh0, bhh1, bhh2};

    // Weights in VGPRs: all 4 gates of unit j, all 3 layers.
    half2v Whh[3][4][10];   // recurrent
    half2v Wih[2][4][10];   // input (layers 1,2)
    float bs[3][4];
    float wx[4];            // layer-0 scalar input weights (IN=1)
#pragma unroll
    for (int l = 0; l < 3; ++l) {
#pragma unroll
        for (int gt = 0; gt < 4; ++gt) {
            const int r = gt * HID + j;
#pragma unroll
            for (int k4 = 0; k4 < 5; ++k4) {
                float4 v = *(const float4*)(whh_l[l] + r * HID + 4 * k4);
                Whh[l][gt][2 * k4]     = pack2(v.x, v.y);
                Whh[l][gt][2 * k4 + 1] = pack2(v.z, v.w);
            }
            bs[l][gt] = bih_l[l][r] + bhh_l[l][r];
            if (l == 0) wx[gt] = wih0[r];
            else {
#pragma unroll
                for (int k4 = 0; k4 < 5; ++k4) {
                    float4 v = *(const float4*)(wih_l[l] + r * HID + 4 * k4);
                    Wih[l - 1][gt][2 * k4]     = pack2(v.x, v.y);
                    Wih[l - 1][gt][2 * k4 + 1] = pack2(v.z, v.w);
                }
            }
        }
    }

    // In-register state
    half2v hb2[3][10];      // distributed h_l(t-1), packed half2, all lanes
#pragma unroll
    for (int l = 0; l < 3; ++l)
#pragma unroll
        for (int k = 0; k < 10; ++k) hb2[l][k] = pack2(0.f, 0.f);
    float c[3] = {0.f, 0.f, 0.f};
    float h2f = 0.f;        // final-layer h (f32, own unit)

    __syncthreads();        // x staged (single wave: cheap)

    float xt = xlds[gb == 0 ? 0 : T_LEN];  // x[g][0]

    for (int t = 0; t < T_LEN; ++t) {
        // prefetch next x off the critical path
        float xt_n = (t + 1 < T_LEN) ? xlds[g * T_LEN + t + 1] : 0.f;

#pragma unroll
        for (int l = 0; l < 3; ++l) {
            float pre[4];
#pragma unroll
            for (int gt = 0; gt < 4; ++gt) {
                float s0 = 0.f, s1 = 0.f;
#pragma unroll
                for (int k = 0; k < 5; ++k) {
                    s0 = fdot2_(Whh[l][gt][k],     hb2[l][k],     s0);
                    s1 = fdot2_(Whh[l][gt][k + 5], hb2[l][k + 5], s1);
                }
                float p = bs[l][gt] + s0 + s1;
                if (l == 0) {
                    p += wx[gt] * xt;
                } else {
                    float u0 = 0.f, u1 = 0.f;
#pragma unroll
                    for (int k = 0; k < 5; ++k) {
                        u0 = fdot2_(Wih[l - 1][gt][k],     hb2[l - 1][k],     u0);
                        u1 = fdot2_(Wih[l - 1][gt][k + 5], hb2[l - 1][k + 5], u1);
                    }
                    p += u0 + u1;
                }
                pre[gt] = p;
            }
            // gates: i, f, g, o — all lane-local
            float si = sigm(pre[0]);
            float sf = sigm(pre[1]);
            float tg = tanh_s(pre[2]);
            float so = sigm(pre[3]);
            float cn = sf * c[l] + si * tg;
            c[l] = cn;
            float hn = so * tanh_s(cn);
            // distribute h_l(t) to the group (in-register, no LDS/barrier)
            distribute(hn, gb, hb2[l]);
            if (l == 2) h2f = hn;
        }
        xt = xt_n;
    }

    // FC epilogue
    if (act) hfin[g][j] = h2f;
    __syncthreads();
    if (tid < 2 * G_B) {
        const int gg = tid >> 1, o = tid & 1;
        float acc = fcb[o];
#pragma unroll
        for (int k = 0; k < HID; ++k) {
            acc += fcw[o * HID + k] * hfin[gg][k];
        }
        out[(b_base + gg) * 2 + o] = acc;
    }
}

extern "C" void kernel_launch(void* const* d_in, const int* in_sizes, int n_in,
                              void* d_out, int out_size, void* d_ws, size_t ws_size,
                              hipStream_t stream) {
    const float* x    = (const float*)d_in[0];
    const float* wih0 = (const float*)d_in[1];
    const float* whh0 = (const float*)d_in[2];
    const float* bih0 = (const float*)d_in[3];
    const float* bhh0 = (const float*)d_in[4];
    const float* wih1 = (const float*)d_in[5];
    const float* whh1 = (const float*)d_in[6];
    const float* bih1 = (const float*)d_in[7];
    const float* bhh1 = (const float*)d_in[8];
    const float* wih2 = (const float*)d_in[9];
    const float* whh2 = (const float*)d_in[10];
    const float* bih2 = (const float*)d_in[11];
    const float* bhh2 = (const float*)d_in[12];
    const float* fcw  = (const float*)d_in[13];
    const float* fcb  = (const float*)d_in[14];

    lstm3_wave<<<dim3(NBATCH / G_B), dim3(64), 0, stream>>>(
        x, wih0, whh0, bih0, bhh0,
        wih1, whh1, bih1, bhh1,
        wih2, whh2, bih2, bhh2,
        fcw, fcb, (float*)d_out);
}

// Round 8
// 946.964 us; speedup vs baseline: 2.2784x; 2.2784x over previous
//
#include <hip/hip_runtime.h>

typedef _Float16 half2v __attribute__((ext_vector_type(2)));

#define T_LEN 1024
#define NBATCH 1024
#define HID 20

#if defined(__has_builtin)
#if __has_builtin(__builtin_amdgcn_fdot2)
#define HAVE_FDOT2 1
#endif
#endif

__device__ __forceinline__ float fdot2_(half2v a, half2v b, float c) {
#ifdef HAVE_FDOT2
    return __builtin_amdgcn_fdot2(a, b, c, false);
#else
    return c + (float)a[0] * (float)b[0] + (float)a[1] * (float)b[1];
#endif
}

__device__ __forceinline__ half2v pack2(float a, float b) {
    half2v r; r[0] = (_Float16)a; r[1] = (_Float16)b; return r;
}

__device__ __forceinline__ float tanh_s(float z) {
    return 2.0f / (1.0f + __expf(-2.0f * z)) - 1.0f;
}

// Load 20 f16 (one 24-half / 48B row, 16B-aligned) into 10 half2.
__device__ __forceinline__ void load_h20(const _Float16* row, half2v hp[10]) {
    uint4 q0 = *(const uint4*)(row);
    uint4 q1 = *(const uint4*)(row + 8);
    uint2 q2 = *(const uint2*)(row + 16);
    hp[0] = __builtin_bit_cast(half2v, q0.x);
    hp[1] = __builtin_bit_cast(half2v, q0.y);
    hp[2] = __builtin_bit_cast(half2v, q0.z);
    hp[3] = __builtin_bit_cast(half2v, q0.w);
    hp[4] = __builtin_bit_cast(half2v, q1.x);
    hp[5] = __builtin_bit_cast(half2v, q1.y);
    hp[6] = __builtin_bit_cast(half2v, q1.z);
    hp[7] = __builtin_bit_cast(half2v, q1.w);
    hp[8] = __builtin_bit_cast(half2v, q2.x);
    hp[9] = __builtin_bit_cast(half2v, q2.y);
}

// 4-chain own/below dot helper: returns pre-gate pair contributions.
__device__ __forceinline__ void dots20(const half2v W0[10], const half2v W1[10],
                                       const half2v h[10], float& p0, float& p1) {
    float a0 = 0.f, a1 = 0.f, b0 = 0.f, b1 = 0.f;
#pragma unroll
    for (int k = 0; k < 5; ++k) {
        a0 = fdot2_(W0[k],     h[k],     a0);
        a1 = fdot2_(W0[k + 5], h[k + 5], a1);
        b0 = fdot2_(W1[k],     h[k],     b0);
        b1 = fdot2_(W1[k + 5], h[k + 5], b1);
    }
    p0 += a0 + a1;
    p1 += b0 + b1;
}

// Layer-pipelined 3-wave block, 2 TIMESTEPS PER SUPERSTEP (1 barrier / 2 steps).
// Wave l owns layer l; at superstep s it processes t0=2(s-l), t1=t0+1.
// Ring depth 4 (slot = t & 3); parity pair chosen by (s-l)&1.
// Own-h dot partials for the NEXT step are computed right after each h write
// (off the pre-gate critical path). Lanes 0..19 -> i(j),g(j);
// 20..39 -> f(j),o(j); 40..63 idle.
__global__ void __launch_bounds__(192, 3) lstm3_pipe2x(
    const float* __restrict__ x,
    const float* __restrict__ wih0, const float* __restrict__ whh0,
    const float* __restrict__ bih0, const float* __restrict__ bhh0,
    const float* __restrict__ wih1, const float* __restrict__ whh1,
    const float* __restrict__ bih1, const float* __restrict__ bhh1,
    const float* __restrict__ wih2, const float* __restrict__ whh2,
    const float* __restrict__ bih2, const float* __restrict__ bhh2,
    const float* __restrict__ fcw, const float* __restrict__ fcb,
    float* __restrict__ out)
{
    __shared__ __align__(16) float xlds[T_LEN];          // 4 KB staged input
    __shared__ __align__(16) _Float16 rings[3][4][24];   // depth-4 h rings

    const int tid = threadIdx.x;
    const int wv = tid / 64;
    const int lane = tid & 63;
    const int b = blockIdx.x;

    {
        const float4* x4 = (const float4*)(x + (long)b * T_LEN);
        float4* xl4 = (float4*)xlds;
        for (int i = tid; i < T_LEN / 4; i += 192) xl4[i] = x4[i];
        for (int i = tid; i < 3 * 4 * 24; i += 192)
            ((_Float16*)rings)[i] = (_Float16)0.0f;
    }

    const int j = (lane < 40) ? (lane % 20) : 0;
    const bool low = lane < 20;
    const int r0 = low ? j : (HID + j);                  // i-row / f-row
    const int r1 = low ? (2 * HID + j) : (3 * HID + j);  // g-row / o-row
    const int srcl = low ? lane : (lane - 20);
    const bool upd = (lane >= 20) && (lane < 40);

    // gate1 activation: tanh on g-lanes (low), sigmoid on o-lanes (high)
    const float kK = low ? -2.0f : -1.0f;
    const float kA = low ? 2.0f : 1.0f;
    const float kB = low ? -1.0f : 0.0f;

    const float* whh = (wv == 0) ? whh0 : (wv == 1) ? whh1 : whh2;
    const float* wih = (wv == 0) ? wih0 : (wv == 1) ? wih1 : wih2;
    const float* bih = (wv == 0) ? bih0 : (wv == 1) ? bih1 : bih2;
    const float* bhh = (wv == 0) ? bhh0 : (wv == 1) ? bhh1 : bhh2;

    half2v Whh[2][10];
    half2v Wih[2][10];
    float wx0 = 0.0f, wx1 = 0.0f;
    float bias0, bias1;
    {
#pragma unroll
        for (int k4 = 0; k4 < 5; ++k4) {
            float4 v0 = *(const float4*)(whh + r0 * HID + 4 * k4);
            Whh[0][2 * k4]     = pack2(v0.x, v0.y);
            Whh[0][2 * k4 + 1] = pack2(v0.z, v0.w);
            float4 v1 = *(const float4*)(whh + r1 * HID + 4 * k4);
            Whh[1][2 * k4]     = pack2(v1.x, v1.y);
            Whh[1][2 * k4 + 1] = pack2(v1.z, v1.w);
        }
        bias0 = bih[r0] + bhh[r0];
        bias1 = bih[r1] + bhh[r1];
        if (wv == 0) {
            wx0 = wih[r0];  // w_ih0 is (80,1)
            wx1 = wih[r1];
        } else {
#pragma unroll
            for (int k4 = 0; k4 < 5; ++k4) {
                float4 v0 = *(const float4*)(wih + r0 * HID + 4 * k4);
                Wih[0][2 * k4]     = pack2(v0.x, v0.y);
                Wih[0][2 * k4 + 1] = pack2(v0.z, v0.w);
                float4 v1 = *(const float4*)(wih + r1 * HID + 4 * k4);
                Wih[1][2 * k4]     = pack2(v1.x, v1.y);
                Wih[1][2 * k4 + 1] = pack2(v1.z, v1.w);
            }
        }
    }

    _Float16* const own_base = &rings[wv][0][0];
    const _Float16* const bel_base = (wv > 0) ? &rings[wv - 1][0][0]
                                              : &rings[0][0][0];

    float c = 0.0f;                      // cell state (lanes 20..39)
    float oA0 = 0.f, oA1 = 0.f;          // own-h partials for next step A

    __syncthreads();

    for (int s = 0; s < T_LEN / 2 + 2; ++s) {
        const int m = s - wv;            // wave-local superstep index
        if (m >= 0 && m < T_LEN / 2) {
            const int off = (m & 1) * 48;       // slots {0,1} or {2,3}
            const int t0 = 2 * m;
            _Float16* const wA = own_base + off;
            _Float16* const wB = own_base + off + 24;

            // --- pre-gates: below-h reads + ih-dots for BOTH steps, up front
            float preA0 = bias0 + oA0, preA1 = bias1 + oA1;
            float preB0 = bias0,       preB1 = bias1;
            if (wv == 0) {
                preA0 += wx0 * xlds[t0];  preA1 += wx1 * xlds[t0];
                preB0 += wx0 * xlds[t0 + 1]; preB1 += wx1 * xlds[t0 + 1];
            } else {
                half2v hbA[10], hbB[10];
                load_h20(bel_base + off, hbA);
                load_h20(bel_base + off + 24, hbB);
                dots20(Wih[0], Wih[1], hbA, preA0, preA1);
                dots20(Wih[0], Wih[1], hbB, preB0, preB1);
            }

            // --- step A (t0)
            {
                float a0 = 1.0f / (1.0f + __expf(-preA0));        // sig i/f
                float a1 = kA / (1.0f + __expf(kK * preA1)) + kB; // tanh g / sig o
                float uf = __shfl(a0 * a1, srcl, 64);
                if (upd) {
                    c = a0 * c + uf;
                    wA[j] = (_Float16)(a1 * tanh_s(c));
                }
            }
            // own-h(t0) readback + dots -> step B partials (in-order DS)
            {
                half2v ho[10];
                load_h20(wA, ho);
                dots20(Whh[0], Whh[1], ho, preB0, preB1);
            }

            // --- step B (t1)
            {
                float a0 = 1.0f / (1.0f + __expf(-preB0));
                float a1 = kA / (1.0f + __expf(kK * preB1)) + kB;
                float uf = __shfl(a0 * a1, srcl, 64);
                if (upd) {
                    c = a0 * c + uf;
                    wB[j] = (_Float16)(a1 * tanh_s(c));
                }
            }
            // own-h(t1) readback + dots -> next superstep's step A partials
            {
                half2v ho[10];
                load_h20(wB, ho);
                oA0 = 0.f; oA1 = 0.f;
                dots20(Whh[0], Whh[1], ho, oA0, oA1);
            }
        }
        __syncthreads();  // publish this superstep's h to the wave above
    }

    // FC epilogue: h2(T-1), slot (T_LEN-1)&3 = 3
    if (tid < 2) {
        float acc = fcb[tid];
        const _Float16* h2 = &rings[2][3][0];
#pragma unroll
        for (int k = 0; k < HID; ++k) {
            acc += fcw[tid * HID + k] * (float)h2[k];
        }
        out[b * 2 + tid] = acc;
    }
}

extern "C" void kernel_launch(void* const* d_in, const int* in_sizes, int n_in,
                              void* d_out, int out_size, void* d_ws, size_t ws_size,
                              hipStream_t stream) {
    const float* x    = (const float*)d_in[0];
    const float* wih0 = (const float*)d_in[1];
    const float* whh0 = (const float*)d_in[2];
    const float* bih0 = (const float*)d_in[3];
    const float* bhh0 = (const float*)d_in[4];
    const float* wih1 = (const float*)d_in[5];
    const float* whh1 = (const float*)d_in[6];
    const float* bih1 = (const float*)d_in[7];
    const float* bhh1 = (const float*)d_in[8];
    const float* wih2 = (const float*)d_in[9];
    const float* whh2 = (const float*)d_in[10];
    const float* bih2 = (const float*)d_in[11];
    const float* bhh2 = (const float*)d_in[12];
    const float* fcw  = (const float*)d_in[13];
    const float* fcb  = (const float*)d_in[14];

    lstm3_pipe2x<<<dim3(NBATCH), dim3(192), 0, stream>>>(
        x, wih0, whh0, bih0, bhh0,
        wih1, whh1, bih1, bhh1,
        wih2, whh2, bih2, bhh2,
        fcw, fcb, (float*)d_out);
}

// Round 9
// 861.333 us; speedup vs baseline: 2.5050x; 1.0994x over previous
//
#include <hip/hip_runtime.h>

typedef _Float16 half2v __attribute__((ext_vector_type(2)));

#define T_LEN 1024
#define NBATCH 1024
#define HID 20
#define G_B 2   // batch elements per wave (lane groups of 20)

#if defined(__has_builtin)
#if __has_builtin(__builtin_amdgcn_fdot2)
#define HAVE_FDOT2 1
#endif
#endif

__device__ __forceinline__ float fdot2_(half2v a, half2v b, float c) {
#ifdef HAVE_FDOT2
    return __builtin_amdgcn_fdot2(a, b, c, false);
#else
    return c + (float)a[0] * (float)b[0] + (float)a[1] * (float)b[1];
#endif
}

__device__ __forceinline__ half2v pack2(float a, float b) {
    half2v r; r[0] = (_Float16)a; r[1] = (_Float16)b; return r;
}

__device__ __forceinline__ float sigm(float z) {
    return 1.0f / (1.0f + __expf(-z));
}
__device__ __forceinline__ float tanh_s(float z) {
    return 2.0f / (1.0f + __expf(-2.0f * z)) - 1.0f;
}

// Load 20 f16 (one 24-half / 48B row, 16B-aligned) into 10 half2.
__device__ __forceinline__ void load_h20(const _Float16* row, half2v hp[10]) {
    uint4 q0 = *(const uint4*)(row);
    uint4 q1 = *(const uint4*)(row + 8);
    uint2 q2 = *(const uint2*)(row + 16);
    hp[0] = __builtin_bit_cast(half2v, q0.x);
    hp[1] = __builtin_bit_cast(half2v, q0.y);
    hp[2] = __builtin_bit_cast(half2v, q0.z);
    hp[3] = __builtin_bit_cast(half2v, q0.w);
    hp[4] = __builtin_bit_cast(half2v, q1.x);
    hp[5] = __builtin_bit_cast(half2v, q1.y);
    hp[6] = __builtin_bit_cast(half2v, q1.z);
    hp[7] = __builtin_bit_cast(half2v, q1.w);
    hp[8] = __builtin_bit_cast(half2v, q2.x);
    hp[9] = __builtin_bit_cast(half2v, q2.y);
}

// 20-element dot, two independent depth-5 chains.
__device__ __forceinline__ float dot20s(const half2v W[10], const half2v h[10]) {
    float a0 = 0.f, a1 = 0.f;
#pragma unroll
    for (int k = 0; k < 5; ++k) {
        a0 = fdot2_(W[k],     h[k],     a0);
        a1 = fdot2_(W[k + 5], h[k + 5], a1);
    }
    return a0 + a1;
}

// Layer-pipelined 3-wave block, 2 batches/wave, 4 gates/lane (NO shfl).
// Wave l owns layer l for both batches; superstep s processes t0=2(s-l), t0+1.
// Lane = g*20 + j (g=batch group 0/1, j=hidden unit); lanes 40..63 idle.
// Each lane holds all 4 gate rows (i,f,g,o) of unit j: c/h update lane-local.
// h handoff: depth-4 LDS ring (slot = t&3), rows of 24 halfs per batch.
// Own-h dots computed right after each h write (same-wave in-order DS).
__global__ void __launch_bounds__(192, 2) lstm3_pipe4g(
    const float* __restrict__ x,
    const float* __restrict__ wih0, const float* __restrict__ whh0,
    const float* __restrict__ bih0, const float* __restrict__ bhh0,
    const float* __restrict__ wih1, const float* __restrict__ whh1,
    const float* __restrict__ bih1, const float* __restrict__ bhh1,
    const float* __restrict__ wih2, const float* __restrict__ whh2,
    const float* __restrict__ bih2, const float* __restrict__ bhh2,
    const float* __restrict__ fcw, const float* __restrict__ fcb,
    float* __restrict__ out)
{
    __shared__ __align__(16) float xlds[G_B * T_LEN];     // 8 KB staged input
    __shared__ __align__(16) _Float16 rings[3][4][G_B * 24];  // depth-4 rings

    const int tid = threadIdx.x;
    const int wv = tid / 64;
    const int lane = tid & 63;
    const long b_base = (long)blockIdx.x * G_B;

    {
        const float4* x4 = (const float4*)(x + b_base * T_LEN);
        float4* xl4 = (float4*)xlds;
        for (int i = tid; i < G_B * T_LEN / 4; i += 192) xl4[i] = x4[i];
        for (int i = tid; i < 3 * 4 * G_B * 24; i += 192)
            ((_Float16*)rings)[i] = (_Float16)0.0f;
    }

    const bool act = lane < G_B * HID;
    const int g = act ? (lane / HID) : 0;
    const int j = act ? (lane % HID) : 0;

    const float* whh = (wv == 0) ? whh0 : (wv == 1) ? whh1 : whh2;
    const float* wih = (wv == 0) ? wih0 : (wv == 1) ? wih1 : wih2;
    const float* bih = (wv == 0) ? bih0 : (wv == 1) ? bih1 : bih2;
    const float* bhh = (wv == 0) ? bhh0 : (wv == 1) ? bhh1 : bhh2;

    // All 4 gate rows (i,f,g,o) of unit j in VGPRs.
    half2v Whh[4][10];
    half2v Wih[4][10];   // used by waves 1,2
    float bias[4];
    float wx[4] = {0.f, 0.f, 0.f, 0.f};  // wave 0 scalar input weights
#pragma unroll
    for (int gt = 0; gt < 4; ++gt) {
        const int r = gt * HID + j;
#pragma unroll
        for (int k4 = 0; k4 < 5; ++k4) {
            float4 v = *(const float4*)(whh + r * HID + 4 * k4);
            Whh[gt][2 * k4]     = pack2(v.x, v.y);
            Whh[gt][2 * k4 + 1] = pack2(v.z, v.w);
        }
        bias[gt] = bih[r] + bhh[r];
        if (wv == 0) {
            wx[gt] = wih[r];  // w_ih0 is (80,1)
        } else {
#pragma unroll
            for (int k4 = 0; k4 < 5; ++k4) {
                float4 v = *(const float4*)(wih + r * HID + 4 * k4);
                Wih[gt][2 * k4]     = pack2(v.x, v.y);
                Wih[gt][2 * k4 + 1] = pack2(v.z, v.w);
            }
        }
    }

    _Float16* const own_base = &rings[wv][0][0];
    const _Float16* const bel_base = (wv > 0) ? &rings[wv - 1][0][0]
                                              : &rings[0][0][0];

    float c = 0.0f;                              // cell state (own unit)
    float oA[4] = {0.f, 0.f, 0.f, 0.f};          // own-h partials (h(-1)=0)

    __syncthreads();

    for (int s = 0; s < T_LEN / 2 + 2; ++s) {
        const int m = s - wv;                    // wave-local superstep
        if (m >= 0 && m < T_LEN / 2) {
            // slot pair {0,1} or {2,3}; batch offset g*24 within each slot
            const int off = (m & 1) * (2 * G_B * 24) + g * 24;
            const int t0 = 2 * m;
            _Float16* const wA = own_base + off;
            _Float16* const wB = own_base + off + G_B * 24;

            float preA[4], preB[4];
#pragma unroll
            for (int gt = 0; gt < 4; ++gt) {
                preA[gt] = bias[gt] + oA[gt];
                preB[gt] = bias[gt];
            }
            if (wv == 0) {
                const float xA = xlds[g * T_LEN + t0];
                const float xB = xlds[g * T_LEN + t0 + 1];
#pragma unroll
                for (int gt = 0; gt < 4; ++gt) {
                    preA[gt] += wx[gt] * xA;
                    preB[gt] += wx[gt] * xB;
                }
            } else {
                half2v hbA[10], hbB[10];
                load_h20(bel_base + off, hbA);
                load_h20(bel_base + off + G_B * 24, hbB);
#pragma unroll
                for (int gt = 0; gt < 4; ++gt) {
                    preA[gt] += dot20s(Wih[gt], hbA);
                    preB[gt] += dot20s(Wih[gt], hbB);
                }
            }

            // --- step A (t0): all gates lane-local
            {
                float si = sigm(preA[0]);
                float sf = sigm(preA[1]);
                float tg = tanh_s(preA[2]);
                float so = sigm(preA[3]);
                c = sf * c + si * tg;
                if (act) wA[j] = (_Float16)(so * tanh_s(c));
            }
            // own-h(t0) readback + dots -> step B (same-wave in-order DS)
            {
                half2v ho[10];
                load_h20(wA, ho);
#pragma unroll
                for (int gt = 0; gt < 4; ++gt) preB[gt] += dot20s(Whh[gt], ho);
            }

            // --- step B (t0+1)
            {
                float si = sigm(preB[0]);
                float sf = sigm(preB[1]);
                float tg = tanh_s(preB[2]);
                float so = sigm(preB[3]);
                c = sf * c + si * tg;
                if (act) wB[j] = (_Float16)(so * tanh_s(c));
            }
            // own-h(t0+1) readback + dots -> next superstep step A
            {
                half2v ho[10];
                load_h20(wB, ho);
#pragma unroll
                for (int gt = 0; gt < 4; ++gt) oA[gt] = dot20s(Whh[gt], ho);
            }
        }
        __syncthreads();  // publish this superstep's h to the wave above
    }

    // FC epilogue: h2(T-1), slot (T_LEN-1)&3 = 3
    if (wv == 2 && lane < 2 * G_B) {
        const int gg = lane >> 1, o = lane & 1;
        float acc = fcb[o];
        const _Float16* h2 = &rings[2][3][gg * 24];
#pragma unroll
        for (int k = 0; k < HID; ++k) {
            acc += fcw[o * HID + k] * (float)h2[k];
        }
        out[(b_base + gg) * 2 + o] = acc;
    }
}

extern "C" void kernel_launch(void* const* d_in, const int* in_sizes, int n_in,
                              void* d_out, int out_size, void* d_ws, size_t ws_size,
                              hipStream_t stream) {
    const float* x    = (const float*)d_in[0];
    const float* wih0 = (const float*)d_in[1];
    const float* whh0 = (const float*)d_in[2];
    const float* bih0 = (const float*)d_in[3];
    const float* bhh0 = (const float*)d_in[4];
    const float* wih1 = (const float*)d_in[5];
    const float* whh1 = (const float*)d_in[6];
    const float* bih1 = (const float*)d_in[7];
    const float* bhh1 = (const float*)d_in[8];
    const float* wih2 = (const float*)d_in[9];
    const float* whh2 = (const float*)d_in[10];
    const float* bih2 = (const float*)d_in[11];
    const float* bhh2 = (const float*)d_in[12];
    const float* fcw  = (const float*)d_in[13];
    const float* fcb  = (const float*)d_in[14];

    lstm3_pipe4g<<<dim3(NBATCH / G_B), dim3(192), 0, stream>>>(
        x, wih0, whh0, bih0, bhh0,
        wih1, whh1, bih1, bhh1,
        wih2, whh2, bih2, bhh2,
        fcw, fcb, (float*)d_out);
}

// Round 10
// 843.709 us; speedup vs baseline: 2.5573x; 1.0209x over previous
//
#include <hip/hip_runtime.h>

typedef _Float16 half2v __attribute__((ext_vector_type(2)));

#define T_LEN 1024
#define NBATCH 1024
#define HID 20
#define G_B 2      // batch elements per wave (lane groups of 20)
#define STEPS 4    // timesteps per superstep (one barrier per STEPS steps)

#if defined(__has_builtin)
#if __has_builtin(__builtin_amdgcn_fdot2)
#define HAVE_FDOT2 1
#endif
#endif

__device__ __forceinline__ float fdot2_(half2v a, half2v b, float c) {
#ifdef HAVE_FDOT2
    return __builtin_amdgcn_fdot2(a, b, c, false);
#else
    return c + (float)a[0] * (float)b[0] + (float)a[1] * (float)b[1];
#endif
}

__device__ __forceinline__ half2v pack2(float a, float b) {
    half2v r; r[0] = (_Float16)a; r[1] = (_Float16)b; return r;
}

__device__ __forceinline__ float sigm(float z) {
    return 1.0f / (1.0f + __expf(-z));
}
__device__ __forceinline__ float tanh_s(float z) {
    return 2.0f / (1.0f + __expf(-2.0f * z)) - 1.0f;
}

// Load 20 f16 (one 24-half / 48B row, 16B-aligned) into 10 half2.
__device__ __forceinline__ void load_h20(const _Float16* row, half2v hp[10]) {
    uint4 q0 = *(const uint4*)(row);
    uint4 q1 = *(const uint4*)(row + 8);
    uint2 q2 = *(const uint2*)(row + 16);
    hp[0] = __builtin_bit_cast(half2v, q0.x);
    hp[1] = __builtin_bit_cast(half2v, q0.y);
    hp[2] = __builtin_bit_cast(half2v, q0.z);
    hp[3] = __builtin_bit_cast(half2v, q0.w);
    hp[4] = __builtin_bit_cast(half2v, q1.x);
    hp[5] = __builtin_bit_cast(half2v, q1.y);
    hp[6] = __builtin_bit_cast(half2v, q1.z);
    hp[7] = __builtin_bit_cast(half2v, q1.w);
    hp[8] = __builtin_bit_cast(half2v, q2.x);
    hp[9] = __builtin_bit_cast(half2v, q2.y);
}

// 20-element dot, two independent depth-5 chains.
__device__ __forceinline__ float dot20s(const half2v W[10], const half2v h[10]) {
    float a0 = 0.f, a1 = 0.f;
#pragma unroll
    for (int k = 0; k < 5; ++k) {
        a0 = fdot2_(W[k],     h[k],     a0);
        a1 = fdot2_(W[k + 5], h[k + 5], a1);
    }
    return a0 + a1;
}

// Layer-pipelined 3-wave block, 2 batches/wave, 4 gates/lane, 4 steps/barrier.
// Wave l owns layer l for both batches; superstep s=m+wv processes
// t = 4m .. 4m+3. Ring depth 8 (slot = t & 7); superstep uses slot quad
// (m&1)*4 + {0..3}. All 4 below-rows + ih-dots hoisted to superstep start
// (independent work that fills the write->readback bubbles). Own-h dots
// computed right after each h write (same-wave in-order DS). x staged
// interleaved [t][g] to avoid bank aliasing between lane groups.
__global__ void __launch_bounds__(192, 2) lstm3_pipe4s(
    const float* __restrict__ x,
    const float* __restrict__ wih0, const float* __restrict__ whh0,
    const float* __restrict__ bih0, const float* __restrict__ bhh0,
    const float* __restrict__ wih1, const float* __restrict__ whh1,
    const float* __restrict__ bih1, const float* __restrict__ bhh1,
    const float* __restrict__ wih2, const float* __restrict__ whh2,
    const float* __restrict__ bih2, const float* __restrict__ bhh2,
    const float* __restrict__ fcw, const float* __restrict__ fcb,
    float* __restrict__ out)
{
    __shared__ __align__(16) float xlds[G_B * T_LEN];        // interleaved [t][g]
    __shared__ __align__(16) _Float16 rings[3][8][G_B * 24]; // depth-8 rings

    const int tid = threadIdx.x;
    const int wv = tid / 64;
    const int lane = tid & 63;
    const long b_base = (long)blockIdx.x * G_B;

    {
        // stage x interleaved: xlds[2*t + g] = x[b_base+g][t]
        const float* xg = x + b_base * T_LEN;
        for (int i = tid; i < G_B * T_LEN; i += 192) {
            const int t = i & (T_LEN - 1);
            const int g = i >> 10;
            xlds[2 * t + g] = xg[i];
        }
        for (int i = tid; i < 3 * 8 * G_B * 24; i += 192)
            ((_Float16*)rings)[i] = (_Float16)0.0f;
    }

    const bool act = lane < G_B * HID;
    const int g = act ? (lane / HID) : 0;
    const int j = act ? (lane % HID) : 0;

    const float* whh = (wv == 0) ? whh0 : (wv == 1) ? whh1 : whh2;
    const float* wih = (wv == 0) ? wih0 : (wv == 1) ? wih1 : wih2;
    const float* bih = (wv == 0) ? bih0 : (wv == 1) ? bih1 : bih2;
    const float* bhh = (wv == 0) ? bhh0 : (wv == 1) ? bhh1 : bhh2;

    // All 4 gate rows (i,f,g,o) of unit j in VGPRs.
    half2v Whh[4][10];
    half2v Wih[4][10];   // waves 1,2
    float bias[4];
    float wx[4] = {0.f, 0.f, 0.f, 0.f};
#pragma unroll
    for (int gt = 0; gt < 4; ++gt) {
        const int r = gt * HID + j;
#pragma unroll
        for (int k4 = 0; k4 < 5; ++k4) {
            float4 v = *(const float4*)(whh + r * HID + 4 * k4);
            Whh[gt][2 * k4]     = pack2(v.x, v.y);
            Whh[gt][2 * k4 + 1] = pack2(v.z, v.w);
        }
        bias[gt] = bih[r] + bhh[r];
        if (wv == 0) {
            wx[gt] = wih[r];  // w_ih0 is (80,1)
        } else {
#pragma unroll
            for (int k4 = 0; k4 < 5; ++k4) {
                float4 v = *(const float4*)(wih + r * HID + 4 * k4);
                Wih[gt][2 * k4]     = pack2(v.x, v.y);
                Wih[gt][2 * k4 + 1] = pack2(v.z, v.w);
            }
        }
    }

    _Float16* const own_base = &rings[wv][0][0];
    const _Float16* const bel_base = (wv > 0) ? &rings[wv - 1][0][0]
                                              : &rings[0][0][0];

    float c = 0.0f;                              // cell state (own unit)
    float oA[4] = {0.f, 0.f, 0.f, 0.f};          // own-h partials (h(-1)=0)

    __syncthreads();

    const int SS = T_LEN / STEPS;  // supersteps per wave
    const int ROW = G_B * 24;      // halfs per timestep slot

    for (int s = 0; s < SS + 2; ++s) {
        const int m = s - wv;
        if (m >= 0 && m < SS) {
            const int qb = (m & 1) * (STEPS * ROW) + g * 24;  // quad base
            const int t0 = STEPS * m;

            // ---- hoisted pre-gates for ALL 4 steps (independent work) ----
            float pre[STEPS][4];
#pragma unroll
            for (int i = 0; i < STEPS; ++i)
#pragma unroll
                for (int gt = 0; gt < 4; ++gt)
                    pre[i][gt] = bias[gt];
#pragma unroll
            for (int gt = 0; gt < 4; ++gt) pre[0][gt] += oA[gt];

            if (wv == 0) {
#pragma unroll
                for (int i = 0; i < STEPS; ++i) {
                    const float xt = xlds[2 * (t0 + i) + g];
#pragma unroll
                    for (int gt = 0; gt < 4; ++gt) pre[i][gt] += wx[gt] * xt;
                }
            } else {
#pragma unroll
                for (int i = 0; i < STEPS; ++i) {
                    half2v hb[10];
                    load_h20(bel_base + qb + i * ROW, hb);
#pragma unroll
                    for (int gt = 0; gt < 4; ++gt)
                        pre[i][gt] += dot20s(Wih[gt], hb);
                }
            }

            // ---- serial chain: 4 steps ----
#pragma unroll
            for (int i = 0; i < STEPS; ++i) {
                float si = sigm(pre[i][0]);
                float sf = sigm(pre[i][1]);
                float tg = tanh_s(pre[i][2]);
                float so = sigm(pre[i][3]);
                c = sf * c + si * tg;
                _Float16* const wp = own_base + qb + i * ROW;
                if (act) wp[j] = (_Float16)(so * tanh_s(c));
                // own-h readback + dots (same-wave in-order DS, no sync)
                half2v ho[10];
                load_h20(wp, ho);
                if (i < STEPS - 1) {
#pragma unroll
                    for (int gt = 0; gt < 4; ++gt)
                        pre[i + 1][gt] += dot20s(Whh[gt], ho);
                } else {
#pragma unroll
                    for (int gt = 0; gt < 4; ++gt)
                        oA[gt] = dot20s(Whh[gt], ho);
                }
            }
        }
        __syncthreads();  // publish this superstep's 4 rows to the wave above
    }

    // FC epilogue: h2(T-1), slot (T_LEN-1)&7 = 7
    if (wv == 2 && lane < 2 * G_B) {
        const int gg = lane >> 1, o = lane & 1;
        float acc = fcb[o];
        const _Float16* h2 = &rings[2][7][gg * 24];
#pragma unroll
        for (int k = 0; k < HID; ++k) {
            acc += fcw[o * HID + k] * (float)h2[k];
        }
        out[(b_base + gg) * 2 + o] = acc;
    }
}

extern "C" void kernel_launch(void* const* d_in, const int* in_sizes, int n_in,
                              void* d_out, int out_size, void* d_ws, size_t ws_size,
                              hipStream_t stream) {
    const float* x    = (const float*)d_in[0];
    const float* wih0 = (const float*)d_in[1];
    const float* whh0 = (const float*)d_in[2];
    const float* bih0 = (const float*)d_in[3];
    const float* bhh0 = (const float*)d_in[4];
    const float* wih1 = (const float*)d_in[5];
    const float* whh1 = (const float*)d_in[6];
    const float* bih1 = (const float*)d_in[7];
    const float* bhh1 = (const float*)d_in[8];
    const float* wih2 = (const float*)d_in[9];
    const float* whh2 = (const float*)d_in[10];
    const float* bih2 = (const float*)d_in[11];
    const float* bhh2 = (const float*)d_in[12];
    const float* fcw  = (const float*)d_in[13];
    const float* fcb  = (const float*)d_in[14];

    lstm3_pipe4s<<<dim3(NBATCH / G_B), dim3(192), 0, stream>>>(
        x, wih0, whh0, bih0, bhh0,
        wih1, whh1, bih1, bhh1,
        wih2, whh2, bih2, bhh2,
        fcw, fcb, (float*)d_out);
}